// Round 13
// baseline (3884.532 us; speedup 1.0000x reference)
//
#include <hip/hip_runtime.h>
#include <stdint.h>

#define HW 25600
#define C  2048
#define K  10
#define NITER 20
#define RTOL_ 1e-5f
#define ATOL_ 1e-6f

// ---------------- device state (fully re-derived every launch) ----------------
__device__ __align__(4) unsigned char g_valid[HW];
__device__ __align__(4) unsigned char g_labels[HW];
__device__ float g_tok_sq[HW];
__device__ float g_r[HW];
__device__ __align__(16) float g_cent[K * C];
__device__ __align__(16) float g_sums[K * C];
__device__ float g_csq[K];
__device__ int   g_counts[K];
__device__ unsigned g_done;
// scratch for parallel f64 partial reductions (f64 reassociation is safe:
// noise ~1e-16 rel, absorbed by the final f64->f32 rounding — R10-R12 evidence)
__device__ double g_part[8 * K * HW];      // label partial dots (16.4 MB)
__device__ double g_psq[8 * HW];           // prep partial sumsq
__device__ __align__(4) unsigned char g_pany[8 * HW];

// ---------------- prep A: per-chunk f64 partial sumsq + any ----------------
// 200 blocks = 25 hw-blocks (1024 tokens) x 8 c-chunks of 256 channels.
// Each thread owns 4 consecutive tokens -> float4 loads; per-token serial
// f64 FMA chain over cc ascending (bit-identical to R12's per-token chain).
__global__ __launch_bounds__(256) void prepA_kernel(const float* __restrict__ X,
                                                    const float* __restrict__ mask) {
    const int chunk = blockIdx.x & 7;
    const int hw0 = (blockIdx.x >> 3) * 1024 + threadIdx.x * 4;
    const float4 m4 = *(const float4*)(mask + hw0);
    const float mb0 = (m4.x > 0.0f) ? 1.0f : 0.0f;
    const float mb1 = (m4.y > 0.0f) ? 1.0f : 0.0f;
    const float mb2 = (m4.z > 0.0f) ? 1.0f : 0.0f;
    const float mb3 = (m4.w > 0.0f) ? 1.0f : 0.0f;
    const float* xp = X + hw0 + (size_t)(chunk * 256) * HW;
    double a0 = 0.0, a1 = 0.0, a2 = 0.0, a3 = 0.0;
    int n0 = 0, n1 = 0, n2 = 0, n3 = 0;
    for (int cc = 0; cc < 256; ++cc) {
        const float4 x = *(const float4*)(xp + (size_t)cc * HW);
        float v0 = x.x * mb0, v1 = x.y * mb1, v2 = x.z * mb2, v3 = x.w * mb3;
        n0 |= (v0 != 0.0f); n1 |= (v1 != 0.0f);
        n2 |= (v2 != 0.0f); n3 |= (v3 != 0.0f);
        a0 = fma((double)v0, (double)v0, a0);
        a1 = fma((double)v1, (double)v1, a1);
        a2 = fma((double)v2, (double)v2, a2);
        a3 = fma((double)v3, (double)v3, a3);
    }
    double* ps = g_psq + chunk * HW + hw0;
    ps[0] = a0; ps[1] = a1; ps[2] = a2; ps[3] = a3;
    *(uchar4*)&g_pany[chunk * HW + hw0] =
        make_uchar4((unsigned char)n0, (unsigned char)n1,
                    (unsigned char)n2, (unsigned char)n3);
}

// ---------------- threefry2x32 (JAX partitionable), key=(0,42) ----------------
// counter=(hi=0, lo=i); 32-bit draw = out0 ^ out1 (CONFIRMED R6/R10-R12).
__device__ __forceinline__ uint32_t rotl32(uint32_t v, int d) {
    return (v << d) | (v >> (32 - d));
}

// ---------------- prepB + rng fused: tok_sq/valid then r ----------------
__global__ __launch_bounds__(256) void rng_kernel() {
    const int hw = blockIdx.x * 256 + threadIdx.x;
    double s0 = (g_psq[0 * HW + hw] + g_psq[1 * HW + hw]) +
                (g_psq[2 * HW + hw] + g_psq[3 * HW + hw]);
    double s1 = (g_psq[4 * HW + hw] + g_psq[5 * HW + hw]) +
                (g_psq[6 * HW + hw] + g_psq[7 * HW + hw]);
    g_tok_sq[hw] = (float)(s0 + s1);
    int any = 0;
#pragma unroll
    for (int j = 0; j < 8; ++j) any |= g_pany[j * HW + hw];
    g_valid[hw] = any ? 1 : 0;

    const uint32_t k0 = 0u, k1 = 42u;
    uint32_t ks[3] = {k0, k1, k0 ^ k1 ^ 0x1BD11BDAu};
    uint32_t x0 = 0u + ks[0];
    uint32_t x1 = (uint32_t)hw + ks[1];
    const int rot[2][4] = {{13, 15, 26, 6}, {17, 29, 16, 24}};
#pragma unroll
    for (int g = 0; g < 5; ++g) {
#pragma unroll
        for (int j = 0; j < 4; ++j) {
            x0 += x1;
            x1 = rotl32(x1, rot[g & 1][j]);
            x1 ^= x0;
        }
        x0 += ks[(g + 1) % 3];
        x1 += ks[(g + 2) % 3] + (uint32_t)(g + 1);
    }
    uint32_t bits = x0 ^ x1;
    float u = __uint_as_float((bits >> 9) | 0x3f800000u) - 1.0f;
    g_r[hw] = any ? u : 2.0f;
}

// ---------------- init selection + gather + zero + csq ----------------
// Register-cached u64 keys; wave shfl min-reduce; 2 barriers/round.
__global__ __launch_bounds__(1024) void select_kernel(const float* __restrict__ X,
                                                      const float* __restrict__ mask) {
    __shared__ unsigned long long wmin[16];
    __shared__ unsigned long long bcast;
    __shared__ int sh_idx[K];
    const int tid = threadIdx.x;
    const int lane = tid & 63, wv = tid >> 6;
    unsigned long long key[25];
#pragma unroll
    for (int j = 0; j < 25; ++j) {
        const int i = j * 1024 + tid;
        key[j] = ((unsigned long long)__float_as_uint(g_r[i]) << 32) | (unsigned)i;
    }
    for (int round = 0; round < K; ++round) {
        unsigned long long best = ~0ull;
#pragma unroll
        for (int j = 0; j < 25; ++j) best = (key[j] < best) ? key[j] : best;
#pragma unroll
        for (int off = 32; off > 0; off >>= 1) {
            unsigned long long o = __shfl_down(best, off, 64);
            best = (o < best) ? o : best;
        }
        if (lane == 0) wmin[wv] = best;
        __syncthreads();
        if (wv == 0) {
            unsigned long long b = (lane < 16) ? wmin[lane] : ~0ull;
#pragma unroll
            for (int off = 8; off > 0; off >>= 1) {
                unsigned long long o = __shfl_down(b, off, 64);
                b = (o < b) ? o : b;
            }
            if (lane == 0) { bcast = b; sh_idx[round] = (int)(b & 0xffffffffu); }
        }
        __syncthreads();
        const unsigned long long g = bcast;
#pragma unroll
        for (int j = 0; j < 25; ++j) if (key[j] == g) key[j] = ~0ull;
    }
    for (int e = tid; e < K * C; e += 1024) {
        int k = e >> 11, c = e & (C - 1);
        int id = sh_idx[k];
        float mb = (mask[id] > 0.0f) ? 1.0f : 0.0f;
        g_cent[e] = X[(size_t)c * HW + id] * mb;
    }
    if (tid < K) g_counts[tid] = 0;
    if (tid == 0) g_done = 0u;
    __syncthreads();
    // csq: wave per cluster, f64 accumulate -> shuffle reduce -> f32
    if (wv < K) {
        double a = 0.0;
        for (int c = lane; c < C; c += 64) {
            double v = (double)g_cent[wv * C + c];
            a = fma(v, v, a);
        }
#pragma unroll
        for (int off = 32; off > 0; off >>= 1) a += __shfl_down(a, off, 64);
        if (lane == 0) g_csq[wv] = (float)a;
    }
}

// ---------------- label pass 1: token-major f64 partial dots ----------------
// 200 blocks = 25 hw-blocks x 8 c-chunks. 4 tokens/thread, float4 X loads,
// cent via LDS broadcast (all lanes same address -> conflict-free).
// Per-token chain: cc-ascending f64 FMA — bit-identical to R12.
__global__ __launch_bounds__(256) void label1_kernel(const float* __restrict__ X) {
    if (g_done) return;
    const int chunk = blockIdx.x & 7;
    const int hw0 = (blockIdx.x >> 3) * 1024 + threadIdx.x * 4;
    const int c0 = chunk * 256;
    __shared__ double scent[K][256];  // 20 KB
    const int t = threadIdx.x;
    for (int j = t; j < K * 256; j += 256)
        scent[j >> 8][j & 255] = (double)g_cent[(j >> 8) * C + c0 + (j & 255)];
    __syncthreads();
    double acc[4][K];
#pragma unroll
    for (int j = 0; j < 4; ++j)
#pragma unroll
        for (int k = 0; k < K; ++k) acc[j][k] = 0.0;
    const float* xp = X + hw0 + (size_t)c0 * HW;
    for (int cc = 0; cc < 256; ++cc) {
        const float4 x = *(const float4*)(xp + (size_t)cc * HW);
        const double x0 = (double)x.x, x1 = (double)x.y;
        const double x2 = (double)x.z, x3 = (double)x.w;
#pragma unroll
        for (int k = 0; k < K; ++k) {
            const double cv = scent[k][cc];
            acc[0][k] = fma(x0, cv, acc[0][k]);
            acc[1][k] = fma(x1, cv, acc[1][k]);
            acc[2][k] = fma(x2, cv, acc[2][k]);
            acc[3][k] = fma(x3, cv, acc[3][k]);
        }
    }
#pragma unroll
    for (int k = 0; k < K; ++k) {
        double* pp = g_part + (chunk * K + k) * HW + hw0;
        pp[0] = acc[0][k]; pp[1] = acc[1][k];
        pp[2] = acc[2][k]; pp[3] = acc[3][k];
    }
}

// ---------------- label pass 2: combine, f32 d2 grid, argmin, hist ----------------
__global__ __launch_bounds__(256) void label2_kernel() {
#pragma clang fp contract(off)
    if (g_done) return;
    __shared__ int shist[K];
    const int t = threadIdx.x;
    if (t < K) shist[t] = 0;
    __syncthreads();
    const int hw = blockIdx.x * 256 + t;
    const float tsq = g_tok_sq[hw];
    float best = INFINITY;
    int bl = 0;
#pragma unroll
    for (int k = 0; k < K; ++k) {
        double p0 = g_part[(0 * K + k) * HW + hw], p1 = g_part[(1 * K + k) * HW + hw];
        double p2 = g_part[(2 * K + k) * HW + hw], p3 = g_part[(3 * K + k) * HW + hw];
        double p4 = g_part[(4 * K + k) * HW + hw], p5 = g_part[(5 * K + k) * HW + hw];
        double p6 = g_part[(6 * K + k) * HW + hw], p7 = g_part[(7 * K + k) * HW + hw];
        double d = ((p0 + p1) + (p2 + p3)) + ((p4 + p5) + (p6 + p7));
        float dotf = (float)d;               // correctly-rounded f32 dot
        float twod = 2.0f * dotf;            // exact
        float d2 = (tsq - twod) + g_csq[k];  // reference's f32 grid
        if (d2 < best) { best = d2; bl = k; }
    }
    const int valid = g_valid[hw];
    g_labels[hw] = valid ? (unsigned char)bl : (unsigned char)255;
    if (valid) atomicAdd(&shist[bl], 1);
    __syncthreads();
    if (t < K) atomicAdd(&g_counts[t], shist[t]);
}

// ---------------- sum pass: block per channel, 4 waves x quarter-row ----------------
__global__ __launch_bounds__(256) void sum_kernel(const float* __restrict__ X) {
    if (g_done) return;
    const int c = blockIdx.x;
    const int wv = threadIdx.x >> 6, lane = threadIdx.x & 63;
    const int base = wv * (HW / 4);
    const float4* xr = (const float4*)(X + (size_t)c * HW + base);
    const unsigned* lw = (const unsigned*)(g_labels + base);
    double acc[K];
#pragma unroll
    for (int k = 0; k < K; ++k) acc[k] = 0.0;
    for (int t = 0; t < 25; ++t) {
        const int idx = t * 64 + lane;
        const float4 x = xr[idx];
        const unsigned w = lw[idx];
        const int l0 = (int)(w & 255u), l1 = (int)((w >> 8) & 255u);
        const int l2 = (int)((w >> 16) & 255u), l3 = (int)(w >> 24);
        const double x0 = (double)x.x, x1 = (double)x.y;
        const double x2 = (double)x.z, x3 = (double)x.w;
#pragma unroll
        for (int k = 0; k < K; ++k) {
            double a = acc[k];
            a += (l0 == k) ? x0 : 0.0;
            a += (l1 == k) ? x1 : 0.0;
            a += (l2 == k) ? x2 : 0.0;
            a += (l3 == k) ? x3 : 0.0;
            acc[k] = a;
        }
    }
#pragma unroll
    for (int k = 0; k < K; ++k) {
#pragma unroll
        for (int off = 32; off > 0; off >>= 1) acc[k] += __shfl_down(acc[k], off, 64);
    }
    __shared__ double comb[4][K];
    if (lane == 0) {
#pragma unroll
        for (int k = 0; k < K; ++k) comb[wv][k] = acc[k];
    }
    __syncthreads();
    if (threadIdx.x < K) {
        const int k = threadIdx.x;
        double s = (comb[0][k] + comb[1][k]) + (comb[2][k] + comb[3][k]);
        g_sums[k * C + c] = (float)s;
    }
}

// ---------------- update / convergence / csq ----------------
__global__ __launch_bounds__(1024) void update_kernel(int last, float* __restrict__ out) {
#pragma clang fp contract(off)
    __shared__ float sh_counts[K];
    __shared__ int s_conv;
    __shared__ unsigned s_done;
    const int tid = threadIdx.x;
    if (tid == 0) { s_conv = 1; s_done = g_done; }
    if (tid < K) sh_counts[tid] = (float)g_counts[tid];
    __syncthreads();
    const bool dn = (s_done != 0);
    float newv[20], oldv[20];
    int convLocal = 1;
#pragma unroll
    for (int j = 0; j < 20; ++j) {
        int e = tid + j * 1024;
        int k = e >> 11;
        float cnt = sh_counts[k];
        float cv = g_cent[e];
        float nv = (cnt > 0.0f) ? (g_sums[e] / fmaxf(cnt, 1.0f)) : cv;
        newv[j] = nv;
        oldv[j] = cv;
        float tol = RTOL_ * fabsf(nv);   // rounded mul
        tol = ATOL_ + tol;               // rounded add
        float diff = fabsf(cv - nv);
        if (!(diff <= tol)) convLocal = 0;
    }
    if (!convLocal) atomicAnd(&s_conv, 0);
    __syncthreads();
    const bool conv = (s_conv != 0);
    const bool upd = (!dn && !conv);
#pragma unroll
    for (int j = 0; j < 20; ++j) {
        int e = tid + j * 1024;
        float fv = upd ? newv[j] : oldv[j];
        if (upd) g_cent[e] = fv;
        if (last) out[e] = fv;
    }
    if (tid == 0 && conv && !dn) g_done = 1u;
    if (tid < K) g_counts[tid] = 0;
    __syncthreads();
    const int wv = tid >> 6, lane = tid & 63;
    if (wv < K) {
        double a = 0.0;
        for (int c = lane; c < C; c += 64) {
            double v = (double)g_cent[wv * C + c];
            a = fma(v, v, a);
        }
#pragma unroll
        for (int off = 32; off > 0; off >>= 1) a += __shfl_down(a, off, 64);
        if (lane == 0) g_csq[wv] = (float)a;
    }
}

extern "C" void kernel_launch(void* const* d_in, const int* in_sizes, int n_in,
                              void* d_out, int out_size, void* d_ws, size_t ws_size,
                              hipStream_t stream) {
    const float* X = (const float*)d_in[0];     // [2048, 160*160] flat
    const float* mask = (const float*)d_in[1];  // [160*160]
    float* out = (float*)d_out;                 // [10, 2048]
    (void)in_sizes; (void)n_in; (void)out_size; (void)d_ws; (void)ws_size;

    prepA_kernel<<<200, 256, 0, stream>>>(X, mask);
    rng_kernel<<<100, 256, 0, stream>>>();
    select_kernel<<<1, 1024, 0, stream>>>(X, mask);
    for (int it = 0; it < NITER; ++it) {
        label1_kernel<<<200, 256, 0, stream>>>(X);
        label2_kernel<<<100, 256, 0, stream>>>();
        sum_kernel<<<C, 256, 0, stream>>>(X);
        update_kernel<<<1, 1024, 0, stream>>>(it == NITER - 1 ? 1 : 0, out);
    }
}

// Round 14
// 2953.926 us; speedup vs baseline: 1.3150x; 1.3150x over previous
//
#include <hip/hip_runtime.h>
#include <stdint.h>

#define HW 25600
#define C  2048
#define K  10
#define NITER 20
#define RTOL_ 1e-5f
#define ATOL_ 1e-6f
#define NCH 16          // label c-chunks
#define CCH (C / NCH)   // 128 channels per chunk

// ---------------- device state (fully re-derived every launch) ----------------
__device__ __align__(4) unsigned char g_valid[HW];
__device__ __align__(4) unsigned char g_labels[HW];
__device__ float g_tok_sq[HW];
__device__ float g_r[HW];
__device__ __align__(16) float g_cent[K * C];
__device__ __align__(16) float g_sums[K * C];
__device__ float g_csq[K];
__device__ int   g_counts[K];
__device__ unsigned g_done;
// scratch for parallel f64 partial reductions (f64 reassociation is safe:
// noise ~1e-16 rel, absorbed by the final f64->f32 rounding — R10-R12 evidence)
__device__ double g_part[NCH * K * HW];    // label partial dots (32.8 MB)
__device__ double g_spart[2 * K * C];      // sum halves (f64)
__device__ double g_psq[8 * HW];           // prep partial sumsq
__device__ __align__(4) unsigned char g_pany[8 * HW];

// ---------------- prep A: per-chunk f64 partial sumsq + any ----------------
// 200 blocks = 25 hw-blocks (1024 tokens) x 8 c-chunks of 256 channels.
__global__ __launch_bounds__(256) void prepA_kernel(const float* __restrict__ X,
                                                    const float* __restrict__ mask) {
    const int chunk = blockIdx.x & 7;
    const int hw0 = (blockIdx.x >> 3) * 1024 + threadIdx.x * 4;
    const float4 m4 = *(const float4*)(mask + hw0);
    const float mb0 = (m4.x > 0.0f) ? 1.0f : 0.0f;
    const float mb1 = (m4.y > 0.0f) ? 1.0f : 0.0f;
    const float mb2 = (m4.z > 0.0f) ? 1.0f : 0.0f;
    const float mb3 = (m4.w > 0.0f) ? 1.0f : 0.0f;
    const float* xp = X + hw0 + (size_t)(chunk * 256) * HW;
    double a0 = 0.0, a1 = 0.0, a2 = 0.0, a3 = 0.0;
    int n0 = 0, n1 = 0, n2 = 0, n3 = 0;
    for (int cc = 0; cc < 256; ++cc) {
        const float4 x = *(const float4*)(xp + (size_t)cc * HW);
        float v0 = x.x * mb0, v1 = x.y * mb1, v2 = x.z * mb2, v3 = x.w * mb3;
        n0 |= (v0 != 0.0f); n1 |= (v1 != 0.0f);
        n2 |= (v2 != 0.0f); n3 |= (v3 != 0.0f);
        a0 = fma((double)v0, (double)v0, a0);
        a1 = fma((double)v1, (double)v1, a1);
        a2 = fma((double)v2, (double)v2, a2);
        a3 = fma((double)v3, (double)v3, a3);
    }
    double* ps = g_psq + chunk * HW + hw0;
    ps[0] = a0; ps[1] = a1; ps[2] = a2; ps[3] = a3;
    *(uchar4*)&g_pany[chunk * HW + hw0] =
        make_uchar4((unsigned char)n0, (unsigned char)n1,
                    (unsigned char)n2, (unsigned char)n3);
}

// ---------------- threefry2x32 (JAX partitionable), key=(0,42) ----------------
// counter=(hi=0, lo=i); 32-bit draw = out0 ^ out1 (CONFIRMED R6/R10-R13).
__device__ __forceinline__ uint32_t rotl32(uint32_t v, int d) {
    return (v << d) | (v >> (32 - d));
}

// ---------------- prepB + rng fused: tok_sq/valid then r ----------------
__global__ __launch_bounds__(256) void rng_kernel() {
    const int hw = blockIdx.x * 256 + threadIdx.x;
    double s0 = (g_psq[0 * HW + hw] + g_psq[1 * HW + hw]) +
                (g_psq[2 * HW + hw] + g_psq[3 * HW + hw]);
    double s1 = (g_psq[4 * HW + hw] + g_psq[5 * HW + hw]) +
                (g_psq[6 * HW + hw] + g_psq[7 * HW + hw]);
    g_tok_sq[hw] = (float)(s0 + s1);
    int any = 0;
#pragma unroll
    for (int j = 0; j < 8; ++j) any |= g_pany[j * HW + hw];
    g_valid[hw] = any ? 1 : 0;

    const uint32_t k0 = 0u, k1 = 42u;
    uint32_t ks[3] = {k0, k1, k0 ^ k1 ^ 0x1BD11BDAu};
    uint32_t x0 = 0u + ks[0];
    uint32_t x1 = (uint32_t)hw + ks[1];
    const int rot[2][4] = {{13, 15, 26, 6}, {17, 29, 16, 24}};
#pragma unroll
    for (int g = 0; g < 5; ++g) {
#pragma unroll
        for (int j = 0; j < 4; ++j) {
            x0 += x1;
            x1 = rotl32(x1, rot[g & 1][j]);
            x1 ^= x0;
        }
        x0 += ks[(g + 1) % 3];
        x1 += ks[(g + 2) % 3] + (uint32_t)(g + 1);
    }
    uint32_t bits = x0 ^ x1;
    float u = __uint_as_float((bits >> 9) | 0x3f800000u) - 1.0f;
    g_r[hw] = any ? u : 2.0f;
}

// ---------------- init selection + gather + zero + csq ----------------
__global__ __launch_bounds__(1024) void select_kernel(const float* __restrict__ X,
                                                      const float* __restrict__ mask) {
    __shared__ unsigned long long wmin[16];
    __shared__ unsigned long long bcast;
    __shared__ int sh_idx[K];
    const int tid = threadIdx.x;
    const int lane = tid & 63, wv = tid >> 6;
    unsigned long long key[25];
#pragma unroll
    for (int j = 0; j < 25; ++j) {
        const int i = j * 1024 + tid;
        key[j] = ((unsigned long long)__float_as_uint(g_r[i]) << 32) | (unsigned)i;
    }
    for (int round = 0; round < K; ++round) {
        unsigned long long best = ~0ull;
#pragma unroll
        for (int j = 0; j < 25; ++j) best = (key[j] < best) ? key[j] : best;
#pragma unroll
        for (int off = 32; off > 0; off >>= 1) {
            unsigned long long o = __shfl_down(best, off, 64);
            best = (o < best) ? o : best;
        }
        if (lane == 0) wmin[wv] = best;
        __syncthreads();
        if (wv == 0) {
            unsigned long long b = (lane < 16) ? wmin[lane] : ~0ull;
#pragma unroll
            for (int off = 8; off > 0; off >>= 1) {
                unsigned long long o = __shfl_down(b, off, 64);
                b = (o < b) ? o : b;
            }
            if (lane == 0) { bcast = b; sh_idx[round] = (int)(b & 0xffffffffu); }
        }
        __syncthreads();
        const unsigned long long g = bcast;
#pragma unroll
        for (int j = 0; j < 25; ++j) if (key[j] == g) key[j] = ~0ull;
    }
    for (int e = tid; e < K * C; e += 1024) {
        int k = e >> 11, c = e & (C - 1);
        int id = sh_idx[k];
        float mb = (mask[id] > 0.0f) ? 1.0f : 0.0f;
        g_cent[e] = X[(size_t)c * HW + id] * mb;
    }
    if (tid < K) g_counts[tid] = 0;
    if (tid == 0) g_done = 0u;
    __syncthreads();
    if (wv < K) {
        double a = 0.0;
        for (int c = lane; c < C; c += 64) {
            double v = (double)g_cent[wv * C + c];
            a = fma(v, v, a);
        }
#pragma unroll
        for (int off = 32; off > 0; off >>= 1) a += __shfl_down(a, off, 64);
        if (lane == 0) g_csq[wv] = (float)a;
    }
}

// ---------------- label pass 1: f64 partial dots, 2 tokens/thread ----------------
// 800 blocks = 50 hw-blocks (512 tokens) x 16 c-chunks of 128 channels.
// float2 X loads (8B/lane coalesced); cent via LDS f64 broadcast.
// Per-token chain: cc-ascending f64 FMA — same rounding class as R10-R12.
__global__ __launch_bounds__(256) void label1_kernel(const float* __restrict__ X) {
    if (g_done) return;
    const int chunk = blockIdx.x & (NCH - 1);
    const int hw0 = (blockIdx.x >> 4) * 512 + threadIdx.x * 2;
    const int c0 = chunk * CCH;
    __shared__ double scent[K][CCH];  // 10 KB
    const int t = threadIdx.x;
    for (int j = t; j < K * CCH; j += 256)
        scent[j / CCH][j & (CCH - 1)] = (double)g_cent[(j / CCH) * C + c0 + (j & (CCH - 1))];
    __syncthreads();
    double acc0[K], acc1[K];
#pragma unroll
    for (int k = 0; k < K; ++k) { acc0[k] = 0.0; acc1[k] = 0.0; }
    const float* xp = X + hw0 + (size_t)c0 * HW;
    for (int cc = 0; cc < CCH; ++cc) {
        const float2 x = *(const float2*)(xp + (size_t)cc * HW);
        const double x0 = (double)x.x, x1 = (double)x.y;
#pragma unroll
        for (int k = 0; k < K; ++k) {
            const double cv = scent[k][cc];
            acc0[k] = fma(x0, cv, acc0[k]);
            acc1[k] = fma(x1, cv, acc1[k]);
        }
    }
#pragma unroll
    for (int k = 0; k < K; ++k) {
        double* pp = g_part + (chunk * K + k) * HW + hw0;
        pp[0] = acc0[k]; pp[1] = acc1[k];
    }
}

// ---------------- label pass 2: combine 16, f32 d2 grid, argmin, hist ----------------
__global__ __launch_bounds__(256) void label2_kernel() {
#pragma clang fp contract(off)
    if (g_done) return;
    __shared__ int shist[K];
    const int t = threadIdx.x;
    if (t < K) shist[t] = 0;
    __syncthreads();
    const int hw = blockIdx.x * 256 + t;
    const float tsq = g_tok_sq[hw];
    float best = INFINITY;
    int bl = 0;
#pragma unroll
    for (int k = 0; k < K; ++k) {
        double p[NCH];
#pragma unroll
        for (int j = 0; j < NCH; ++j) p[j] = g_part[(j * K + k) * HW + hw];
        double q0 = ((p[0] + p[1]) + (p[2] + p[3])) + ((p[4] + p[5]) + (p[6] + p[7]));
        double q1 = ((p[8] + p[9]) + (p[10] + p[11])) + ((p[12] + p[13]) + (p[14] + p[15]));
        double d = q0 + q1;
        float dotf = (float)d;               // correctly-rounded f32 dot
        float twod = 2.0f * dotf;            // exact
        float d2 = (tsq - twod) + g_csq[k];  // reference's f32 grid
        if (d2 < best) { best = d2; bl = k; }
    }
    const int valid = g_valid[hw];
    g_labels[hw] = valid ? (unsigned char)bl : (unsigned char)255;
    if (valid) atomicAdd(&shist[bl], 1);
    __syncthreads();
    if (t < K) atomicAdd(&g_counts[t], shist[t]);
}

// ---------------- sum pass: block per (channel, half) ----------------
// 4096 blocks; 4 waves x eighth-row (3200 elems = 800 float4); f64 acc;
// halves stored f64, combined in update before the single f32 rounding.
__global__ __launch_bounds__(256) void sum_kernel(const float* __restrict__ X) {
    if (g_done) return;
    const int c = blockIdx.x >> 1;
    const int half = blockIdx.x & 1;
    const int wv = threadIdx.x >> 6, lane = threadIdx.x & 63;
    const int base = half * (HW / 2) + wv * (HW / 8);
    const float4* xr = (const float4*)(X + (size_t)c * HW + base);
    const unsigned* lw = (const unsigned*)(g_labels + base);
    double acc[K];
#pragma unroll
    for (int k = 0; k < K; ++k) acc[k] = 0.0;
    for (int t = 0; t < 13; ++t) {
        const int idx = t * 64 + lane;       // float4 index within eighth (800)
        if (idx < 800) {
            const float4 x = xr[idx];
            const unsigned w = lw[idx];
            const int l0 = (int)(w & 255u), l1 = (int)((w >> 8) & 255u);
            const int l2 = (int)((w >> 16) & 255u), l3 = (int)(w >> 24);
            const double x0 = (double)x.x, x1 = (double)x.y;
            const double x2 = (double)x.z, x3 = (double)x.w;
#pragma unroll
            for (int k = 0; k < K; ++k) {
                double a = acc[k];
                a += (l0 == k) ? x0 : 0.0;
                a += (l1 == k) ? x1 : 0.0;
                a += (l2 == k) ? x2 : 0.0;
                a += (l3 == k) ? x3 : 0.0;
                acc[k] = a;
            }
        }
    }
#pragma unroll
    for (int k = 0; k < K; ++k) {
#pragma unroll
        for (int off = 32; off > 0; off >>= 1) acc[k] += __shfl_down(acc[k], off, 64);
    }
    __shared__ double comb[4][K];
    if (lane == 0) {
#pragma unroll
        for (int k = 0; k < K; ++k) comb[wv][k] = acc[k];
    }
    __syncthreads();
    if (threadIdx.x < K) {
        const int k = threadIdx.x;
        double s = (comb[0][k] + comb[1][k]) + (comb[2][k] + comb[3][k]);
        g_spart[(half * K + k) * C + c] = s;
    }
}

// ---------------- update / convergence / csq ----------------
__global__ __launch_bounds__(1024) void update_kernel(int last, float* __restrict__ out) {
#pragma clang fp contract(off)
    __shared__ float sh_counts[K];
    __shared__ int s_conv;
    __shared__ unsigned s_done;
    const int tid = threadIdx.x;
    if (tid == 0) { s_conv = 1; s_done = g_done; }
    if (tid < K) sh_counts[tid] = (float)g_counts[tid];
    __syncthreads();
    const bool dn = (s_done != 0);
    float newv[20], oldv[20];
    int convLocal = 1;
#pragma unroll
    for (int j = 0; j < 20; ++j) {
        int e = tid + j * 1024;
        int k = e >> 11;
        float cnt = sh_counts[k];
        float cv = g_cent[e];
        float sumf = (float)(g_spart[e] + g_spart[K * C + e]);  // f64 halves -> f32 once
        float nv = (cnt > 0.0f) ? (sumf / fmaxf(cnt, 1.0f)) : cv;
        newv[j] = nv;
        oldv[j] = cv;
        float tol = RTOL_ * fabsf(nv);   // rounded mul
        tol = ATOL_ + tol;               // rounded add
        float diff = fabsf(cv - nv);
        if (!(diff <= tol)) convLocal = 0;
    }
    if (!convLocal) atomicAnd(&s_conv, 0);
    __syncthreads();
    const bool conv = (s_conv != 0);
    const bool upd = (!dn && !conv);
#pragma unroll
    for (int j = 0; j < 20; ++j) {
        int e = tid + j * 1024;
        float fv = upd ? newv[j] : oldv[j];
        if (upd) g_cent[e] = fv;
        if (last) out[e] = fv;
    }
    if (tid == 0 && conv && !dn) g_done = 1u;
    if (tid < K) g_counts[tid] = 0;
    __syncthreads();
    const int wv = tid >> 6, lane = tid & 63;
    if (wv < K) {
        double a = 0.0;
        for (int c = lane; c < C; c += 64) {
            double v = (double)g_cent[wv * C + c];
            a = fma(v, v, a);
        }
#pragma unroll
        for (int off = 32; off > 0; off >>= 1) a += __shfl_down(a, off, 64);
        if (lane == 0) g_csq[wv] = (float)a;
    }
}

extern "C" void kernel_launch(void* const* d_in, const int* in_sizes, int n_in,
                              void* d_out, int out_size, void* d_ws, size_t ws_size,
                              hipStream_t stream) {
    const float* X = (const float*)d_in[0];     // [2048, 160*160] flat
    const float* mask = (const float*)d_in[1];  // [160*160]
    float* out = (float*)d_out;                 // [10, 2048]
    (void)in_sizes; (void)n_in; (void)out_size; (void)d_ws; (void)ws_size;

    prepA_kernel<<<200, 256, 0, stream>>>(X, mask);
    rng_kernel<<<100, 256, 0, stream>>>();
    select_kernel<<<1, 1024, 0, stream>>>(X, mask);
    for (int it = 0; it < NITER; ++it) {
        label1_kernel<<<800, 256, 0, stream>>>(X);
        label2_kernel<<<100, 256, 0, stream>>>();
        sum_kernel<<<2 * C, 256, 0, stream>>>(X);
        update_kernel<<<1, 1024, 0, stream>>>(it == NITER - 1 ? 1 : 0, out);
    }
}

// Round 15
// 2446.406 us; speedup vs baseline: 1.5879x; 1.2075x over previous
//
#include <hip/hip_runtime.h>
#include <stdint.h>

#define HW 25600
#define C  2048
#define K  10
#define NITER 20
#define RTOL_ 1e-5f
#define ATOL_ 1e-6f
#define NCH 16          // label c-chunks
#define CCH (C / NCH)   // 128 channels per chunk

// ---------------- device state (fully re-derived every launch) ----------------
__device__ __align__(4) unsigned char g_valid[HW];
__device__ __align__(4) unsigned char g_labels[HW];
__device__ float g_tok_sq[HW];
__device__ float g_r[HW];
__device__ __align__(16) float  g_cent[K * C];
__device__ __align__(16) double g_cent64[K * C];   // f64 mirror for scalar loads
__device__ float g_csq[K];
__device__ int   g_counts[K];
__device__ unsigned g_done;
// scratch for parallel f64 partial reductions (f64 reassociation is safe:
// noise ~1e-16 rel, absorbed by the final f64->f32 rounding — R10-R14 evidence)
__device__ double g_part[NCH * K * HW];    // label partial dots (32.8 MB)
__device__ double g_spart[2 * K * C];      // sum halves (f64)
__device__ double g_psq[8 * HW];           // prep partial sumsq
__device__ __align__(4) unsigned char g_pany[8 * HW];

// ---------------- prep A: per-chunk f64 partial sumsq + any ----------------
__global__ __launch_bounds__(256) void prepA_kernel(const float* __restrict__ X,
                                                    const float* __restrict__ mask) {
    const int chunk = blockIdx.x & 7;
    const int hw0 = (blockIdx.x >> 3) * 1024 + threadIdx.x * 4;
    const float4 m4 = *(const float4*)(mask + hw0);
    const float mb0 = (m4.x > 0.0f) ? 1.0f : 0.0f;
    const float mb1 = (m4.y > 0.0f) ? 1.0f : 0.0f;
    const float mb2 = (m4.z > 0.0f) ? 1.0f : 0.0f;
    const float mb3 = (m4.w > 0.0f) ? 1.0f : 0.0f;
    const float* xp = X + hw0 + (size_t)(chunk * 256) * HW;
    double a0 = 0.0, a1 = 0.0, a2 = 0.0, a3 = 0.0;
    int n0 = 0, n1 = 0, n2 = 0, n3 = 0;
    for (int cc = 0; cc < 256; ++cc) {
        const float4 x = *(const float4*)(xp + (size_t)cc * HW);
        float v0 = x.x * mb0, v1 = x.y * mb1, v2 = x.z * mb2, v3 = x.w * mb3;
        n0 |= (v0 != 0.0f); n1 |= (v1 != 0.0f);
        n2 |= (v2 != 0.0f); n3 |= (v3 != 0.0f);
        a0 = fma((double)v0, (double)v0, a0);
        a1 = fma((double)v1, (double)v1, a1);
        a2 = fma((double)v2, (double)v2, a2);
        a3 = fma((double)v3, (double)v3, a3);
    }
    double* ps = g_psq + chunk * HW + hw0;
    ps[0] = a0; ps[1] = a1; ps[2] = a2; ps[3] = a3;
    *(uchar4*)&g_pany[chunk * HW + hw0] =
        make_uchar4((unsigned char)n0, (unsigned char)n1,
                    (unsigned char)n2, (unsigned char)n3);
}

// ---------------- threefry2x32 (JAX partitionable), key=(0,42) ----------------
// counter=(hi=0, lo=i); 32-bit draw = out0 ^ out1 (CONFIRMED R6/R10-R14).
__device__ __forceinline__ uint32_t rotl32(uint32_t v, int d) {
    return (v << d) | (v >> (32 - d));
}

// ---------------- prepB + rng fused ----------------
__global__ __launch_bounds__(256) void rng_kernel() {
    const int hw = blockIdx.x * 256 + threadIdx.x;
    double s0 = (g_psq[0 * HW + hw] + g_psq[1 * HW + hw]) +
                (g_psq[2 * HW + hw] + g_psq[3 * HW + hw]);
    double s1 = (g_psq[4 * HW + hw] + g_psq[5 * HW + hw]) +
                (g_psq[6 * HW + hw] + g_psq[7 * HW + hw]);
    g_tok_sq[hw] = (float)(s0 + s1);
    int any = 0;
#pragma unroll
    for (int j = 0; j < 8; ++j) any |= g_pany[j * HW + hw];
    g_valid[hw] = any ? 1 : 0;

    const uint32_t k0 = 0u, k1 = 42u;
    uint32_t ks[3] = {k0, k1, k0 ^ k1 ^ 0x1BD11BDAu};
    uint32_t x0 = 0u + ks[0];
    uint32_t x1 = (uint32_t)hw + ks[1];
    const int rot[2][4] = {{13, 15, 26, 6}, {17, 29, 16, 24}};
#pragma unroll
    for (int g = 0; g < 5; ++g) {
#pragma unroll
        for (int j = 0; j < 4; ++j) {
            x0 += x1;
            x1 = rotl32(x1, rot[g & 1][j]);
            x1 ^= x0;
        }
        x0 += ks[(g + 1) % 3];
        x1 += ks[(g + 2) % 3] + (uint32_t)(g + 1);
    }
    uint32_t bits = x0 ^ x1;
    float u = __uint_as_float((bits >> 9) | 0x3f800000u) - 1.0f;
    g_r[hw] = any ? u : 2.0f;
}

// ---------------- init selection + gather + zero + csq ----------------
__global__ __launch_bounds__(1024) void select_kernel(const float* __restrict__ X,
                                                      const float* __restrict__ mask) {
    __shared__ unsigned long long wmin[16];
    __shared__ unsigned long long bcast;
    __shared__ int sh_idx[K];
    const int tid = threadIdx.x;
    const int lane = tid & 63, wv = tid >> 6;
    unsigned long long key[25];
#pragma unroll
    for (int j = 0; j < 25; ++j) {
        const int i = j * 1024 + tid;
        key[j] = ((unsigned long long)__float_as_uint(g_r[i]) << 32) | (unsigned)i;
    }
    for (int round = 0; round < K; ++round) {
        unsigned long long best = ~0ull;
#pragma unroll
        for (int j = 0; j < 25; ++j) best = (key[j] < best) ? key[j] : best;
#pragma unroll
        for (int off = 32; off > 0; off >>= 1) {
            unsigned long long o = __shfl_down(best, off, 64);
            best = (o < best) ? o : best;
        }
        if (lane == 0) wmin[wv] = best;
        __syncthreads();
        if (wv == 0) {
            unsigned long long b = (lane < 16) ? wmin[lane] : ~0ull;
#pragma unroll
            for (int off = 8; off > 0; off >>= 1) {
                unsigned long long o = __shfl_down(b, off, 64);
                b = (o < b) ? o : b;
            }
            if (lane == 0) { bcast = b; sh_idx[round] = (int)(b & 0xffffffffu); }
        }
        __syncthreads();
        const unsigned long long g = bcast;
#pragma unroll
        for (int j = 0; j < 25; ++j) if (key[j] == g) key[j] = ~0ull;
    }
    for (int e = tid; e < K * C; e += 1024) {
        int k = e >> 11, c = e & (C - 1);
        int id = sh_idx[k];
        float mb = (mask[id] > 0.0f) ? 1.0f : 0.0f;
        float v = X[(size_t)c * HW + id] * mb;
        g_cent[e] = v;
        g_cent64[e] = (double)v;
    }
    if (tid < K) g_counts[tid] = 0;
    if (tid == 0) g_done = 0u;
    __syncthreads();
    if (wv < K) {
        double a = 0.0;
        for (int c = lane; c < C; c += 64) {
            double v = (double)g_cent[wv * C + c];
            a = fma(v, v, a);
        }
#pragma unroll
        for (int off = 32; off > 0; off >>= 1) a += __shfl_down(a, off, 64);
        if (lane == 0) g_csq[wv] = (float)a;
    }
}

// ---------------- label pass 1: f64 partial dots, scalar-cached cent ----------------
// 800 blocks = 50 hw-blocks (512 tokens) x 16 c-chunks of 128 channels.
// cent read from global f64 mirror with wave-uniform address -> s_load (K$),
// freeing VALU/LDS. Per-token chain: cc-ascending f64 FMA (same as R12-R14).
__global__ __launch_bounds__(256) void label1_kernel(const float* __restrict__ X) {
    if (g_done) return;
    const int chunk = blockIdx.x & (NCH - 1);
    const int hw0 = (blockIdx.x >> 4) * 512 + threadIdx.x * 2;
    const int c0 = chunk * CCH;
    const double* __restrict__ cp = g_cent64 + c0;  // [k*C + cc], wave-uniform
    double acc0[K], acc1[K];
#pragma unroll
    for (int k = 0; k < K; ++k) { acc0[k] = 0.0; acc1[k] = 0.0; }
    const float* xp = X + hw0 + (size_t)c0 * HW;
#pragma unroll 4
    for (int cc = 0; cc < CCH; ++cc) {
        const float2 x = *(const float2*)(xp + (size_t)cc * HW);
        const double x0 = (double)x.x, x1 = (double)x.y;
#pragma unroll
        for (int k = 0; k < K; ++k) {
            const double cv = cp[k * C + cc];
            acc0[k] = fma(x0, cv, acc0[k]);
            acc1[k] = fma(x1, cv, acc1[k]);
        }
    }
#pragma unroll
    for (int k = 0; k < K; ++k) {
        double2* pp = (double2*)(g_part + (chunk * K + k) * HW + hw0);
        *pp = make_double2(acc0[k], acc1[k]);
    }
}

// ---------------- label pass 2: combine 16, f32 d2 grid, argmin, hist ----------------
__global__ __launch_bounds__(256) void label2_kernel() {
#pragma clang fp contract(off)
    if (g_done) return;
    __shared__ int shist[K];
    const int t = threadIdx.x;
    if (t < K) shist[t] = 0;
    __syncthreads();
    const int hw = blockIdx.x * 256 + t;
    const float tsq = g_tok_sq[hw];
    float best = INFINITY;
    int bl = 0;
#pragma unroll
    for (int k = 0; k < K; ++k) {
        double p[NCH];
#pragma unroll
        for (int j = 0; j < NCH; ++j) p[j] = g_part[(j * K + k) * HW + hw];
        double q0 = ((p[0] + p[1]) + (p[2] + p[3])) + ((p[4] + p[5]) + (p[6] + p[7]));
        double q1 = ((p[8] + p[9]) + (p[10] + p[11])) + ((p[12] + p[13]) + (p[14] + p[15]));
        double d = q0 + q1;
        float dotf = (float)d;               // correctly-rounded f32 dot
        float twod = 2.0f * dotf;            // exact
        float d2 = (tsq - twod) + g_csq[k];  // reference's f32 grid
        if (d2 < best) { best = d2; bl = k; }
    }
    const int valid = g_valid[hw];
    g_labels[hw] = valid ? (unsigned char)bl : (unsigned char)255;
    if (valid) atomicAdd(&shist[bl], 1);
    __syncthreads();
    if (t < K) atomicAdd(&g_counts[t], shist[t]);
}

// ---------------- sum pass: LDS per-lane slot accumulation ----------------
// 4096 blocks = (channel, half); 4 waves x eighth-row; one LDS rmw per element
// into per-lane private slots (stride 11; invalid tokens -> dummy slot 10).
// Per-lane accumulation order identical to R14 -> bit-identical f64 sums.
__global__ __launch_bounds__(256) void sum_kernel(const float* __restrict__ X) {
    if (g_done) return;
    __shared__ double sacc[4][64 * 11];  // 22.5 KB
    const int c = blockIdx.x >> 1;
    const int half = blockIdx.x & 1;
    const int wv = threadIdx.x >> 6, lane = threadIdx.x & 63;
    double* slots = &sacc[wv][lane * 11];
#pragma unroll
    for (int k = 0; k < 11; ++k) slots[k] = 0.0;
    const int base = half * (HW / 2) + wv * (HW / 8);
    const float4* xr = (const float4*)(X + (size_t)c * HW + base);
    const unsigned* lw = (const unsigned*)(g_labels + base);
    for (int t = 0; t < 13; ++t) {
        const int idx = t * 64 + lane;       // float4 index within eighth (800)
        if (idx < 800) {
            const float4 x = xr[idx];
            const unsigned w = lw[idx];
            const int l0 = min((int)(w & 255u), 10);
            const int l1 = min((int)((w >> 8) & 255u), 10);
            const int l2 = min((int)((w >> 16) & 255u), 10);
            const int l3 = min((int)(w >> 24), 10);
            slots[l0] += (double)x.x;
            slots[l1] += (double)x.y;
            slots[l2] += (double)x.z;
            slots[l3] += (double)x.w;
        }
    }
    double acc[K];
#pragma unroll
    for (int k = 0; k < K; ++k) acc[k] = slots[k];
#pragma unroll
    for (int k = 0; k < K; ++k) {
#pragma unroll
        for (int off = 32; off > 0; off >>= 1) acc[k] += __shfl_down(acc[k], off, 64);
    }
    __shared__ double comb[4][K];
    if (lane == 0) {
#pragma unroll
        for (int k = 0; k < K; ++k) comb[wv][k] = acc[k];
    }
    __syncthreads();
    if (threadIdx.x < K) {
        const int k = threadIdx.x;
        double s = (comb[0][k] + comb[1][k]) + (comb[2][k] + comb[3][k]);
        g_spart[(half * K + k) * C + c] = s;
    }
}

// ---------------- update / convergence / csq ----------------
__global__ __launch_bounds__(1024) void update_kernel(int last, float* __restrict__ out) {
#pragma clang fp contract(off)
    __shared__ float sh_counts[K];
    __shared__ int s_conv;
    __shared__ unsigned s_done;
    const int tid = threadIdx.x;
    if (tid == 0) { s_conv = 1; s_done = g_done; }
    if (tid < K) sh_counts[tid] = (float)g_counts[tid];
    __syncthreads();
    const bool dn = (s_done != 0);
    float newv[20], oldv[20];
    int convLocal = 1;
#pragma unroll
    for (int j = 0; j < 20; ++j) {
        int e = tid + j * 1024;
        int k = e >> 11;
        float cnt = sh_counts[k];
        float cv = g_cent[e];
        float sumf = (float)(g_spart[e] + g_spart[K * C + e]);  // f64 halves -> f32 once
        float nv = (cnt > 0.0f) ? (sumf / fmaxf(cnt, 1.0f)) : cv;
        newv[j] = nv;
        oldv[j] = cv;
        float tol = RTOL_ * fabsf(nv);   // rounded mul
        tol = ATOL_ + tol;               // rounded add
        float diff = fabsf(cv - nv);
        if (!(diff <= tol)) convLocal = 0;
    }
    if (!convLocal) atomicAnd(&s_conv, 0);
    __syncthreads();
    const bool conv = (s_conv != 0);
    const bool upd = (!dn && !conv);
#pragma unroll
    for (int j = 0; j < 20; ++j) {
        int e = tid + j * 1024;
        float fv = upd ? newv[j] : oldv[j];
        if (upd) { g_cent[e] = fv; g_cent64[e] = (double)fv; }
        if (last) out[e] = fv;
    }
    if (tid == 0 && conv && !dn) g_done = 1u;
    if (tid < K) g_counts[tid] = 0;
    __syncthreads();
    const int wv = tid >> 6, lane = tid & 63;
    if (wv < K) {
        double a = 0.0;
        for (int c = lane; c < C; c += 64) {
            double v = (double)g_cent[wv * C + c];
            a = fma(v, v, a);
        }
#pragma unroll
        for (int off = 32; off > 0; off >>= 1) a += __shfl_down(a, off, 64);
        if (lane == 0) g_csq[wv] = (float)a;
    }
}

extern "C" void kernel_launch(void* const* d_in, const int* in_sizes, int n_in,
                              void* d_out, int out_size, void* d_ws, size_t ws_size,
                              hipStream_t stream) {
    const float* X = (const float*)d_in[0];     // [2048, 160*160] flat
    const float* mask = (const float*)d_in[1];  // [160*160]
    float* out = (float*)d_out;                 // [10, 2048]
    (void)in_sizes; (void)n_in; (void)out_size; (void)d_ws; (void)ws_size;

    prepA_kernel<<<200, 256, 0, stream>>>(X, mask);
    rng_kernel<<<100, 256, 0, stream>>>();
    select_kernel<<<1, 1024, 0, stream>>>(X, mask);
    for (int it = 0; it < NITER; ++it) {
        label1_kernel<<<800, 256, 0, stream>>>(X);
        label2_kernel<<<100, 256, 0, stream>>>();
        sum_kernel<<<2 * C, 256, 0, stream>>>(X);
        update_kernel<<<1, 1024, 0, stream>>>(it == NITER - 1 ? 1 : 0, out);
    }
}

// Round 16
// 2350.482 us; speedup vs baseline: 1.6527x; 1.0408x over previous
//
#include <hip/hip_runtime.h>
#include <stdint.h>

#define HW 25600
#define C  2048
#define K  10
#define NITER 20
#define RTOL_ 1e-5f
#define ATOL_ 1e-6f
#define NCH 8           // label c-chunks
#define CCH (C / NCH)   // 256 channels per chunk

// ---------------- device state (fully re-derived every launch) ----------------
__device__ __align__(4) unsigned char g_valid[HW];
__device__ __align__(4) unsigned char g_labels[HW];
__device__ float g_tok_sq[HW];
__device__ float g_r[HW];
__device__ __align__(16) float  g_cent[K * C];
__device__ __align__(16) double g_cent64[K * C];   // f64 mirror for scalar loads
__device__ float g_csq[K];
__device__ int   g_counts[K];
__device__ unsigned g_done;
// scratch for parallel f64 partial reductions (f64 reassociation is safe:
// noise ~1e-16 rel, absorbed by the final f64->f32 rounding — R10-R15 evidence)
__device__ double g_part[NCH * K * HW];    // label partial dots (16.4 MB)
__device__ double g_spart[K * C];          // channel sums (f64)
__device__ double g_psq[8 * HW];           // prep partial sumsq
__device__ __align__(4) unsigned char g_pany[8 * HW];

// ---------------- prep A: per-chunk f64 partial sumsq + any ----------------
// 800 blocks = 100 hw-blocks x 8 c-chunks of 256 channels. 1 token/thread;
// per-token cc-ascending chain — bit-identical values to R15.
__global__ __launch_bounds__(256) void prepA_kernel(const float* __restrict__ X,
                                                    const float* __restrict__ mask) {
    const int chunk = blockIdx.x & 7;
    const int hw = (blockIdx.x >> 3) * 256 + threadIdx.x;
    const float mb = (mask[hw] > 0.0f) ? 1.0f : 0.0f;
    const float* xp = X + hw + (size_t)(chunk * 256) * HW;
    double a = 0.0;
    int n = 0;
    for (int cc = 0; cc < 256; ++cc) {
        float v = xp[(size_t)cc * HW] * mb;   // exact f32 product (mb in {0,1})
        n |= (v != 0.0f);
        a = fma((double)v, (double)v, a);
    }
    g_psq[chunk * HW + hw] = a;
    g_pany[chunk * HW + hw] = (unsigned char)n;
}

// ---------------- threefry2x32 (JAX partitionable), key=(0,42) ----------------
// counter=(hi=0, lo=i); 32-bit draw = out0 ^ out1 (CONFIRMED R6/R10-R15).
__device__ __forceinline__ uint32_t rotl32(uint32_t v, int d) {
    return (v << d) | (v >> (32 - d));
}

// ---------------- prepB + rng fused ----------------
__global__ __launch_bounds__(256) void rng_kernel() {
    const int hw = blockIdx.x * 256 + threadIdx.x;
    double s0 = (g_psq[0 * HW + hw] + g_psq[1 * HW + hw]) +
                (g_psq[2 * HW + hw] + g_psq[3 * HW + hw]);
    double s1 = (g_psq[4 * HW + hw] + g_psq[5 * HW + hw]) +
                (g_psq[6 * HW + hw] + g_psq[7 * HW + hw]);
    g_tok_sq[hw] = (float)(s0 + s1);
    int any = 0;
#pragma unroll
    for (int j = 0; j < 8; ++j) any |= g_pany[j * HW + hw];
    g_valid[hw] = any ? 1 : 0;

    const uint32_t k0 = 0u, k1 = 42u;
    uint32_t ks[3] = {k0, k1, k0 ^ k1 ^ 0x1BD11BDAu};
    uint32_t x0 = 0u + ks[0];
    uint32_t x1 = (uint32_t)hw + ks[1];
    const int rot[2][4] = {{13, 15, 26, 6}, {17, 29, 16, 24}};
#pragma unroll
    for (int g = 0; g < 5; ++g) {
#pragma unroll
        for (int j = 0; j < 4; ++j) {
            x0 += x1;
            x1 = rotl32(x1, rot[g & 1][j]);
            x1 ^= x0;
        }
        x0 += ks[(g + 1) % 3];
        x1 += ks[(g + 2) % 3] + (uint32_t)(g + 1);
    }
    uint32_t bits = x0 ^ x1;
    float u = __uint_as_float((bits >> 9) | 0x3f800000u) - 1.0f;
    g_r[hw] = any ? u : 2.0f;
}

// ---------------- init selection + gather + zero + csq ----------------
__global__ __launch_bounds__(1024) void select_kernel(const float* __restrict__ X,
                                                      const float* __restrict__ mask) {
    __shared__ unsigned long long wmin[16];
    __shared__ unsigned long long bcast;
    __shared__ int sh_idx[K];
    const int tid = threadIdx.x;
    const int lane = tid & 63, wv = tid >> 6;
    unsigned long long key[25];
#pragma unroll
    for (int j = 0; j < 25; ++j) {
        const int i = j * 1024 + tid;
        key[j] = ((unsigned long long)__float_as_uint(g_r[i]) << 32) | (unsigned)i;
    }
    for (int round = 0; round < K; ++round) {
        unsigned long long best = ~0ull;
#pragma unroll
        for (int j = 0; j < 25; ++j) best = (key[j] < best) ? key[j] : best;
#pragma unroll
        for (int off = 32; off > 0; off >>= 1) {
            unsigned long long o = __shfl_down(best, off, 64);
            best = (o < best) ? o : best;
        }
        if (lane == 0) wmin[wv] = best;
        __syncthreads();
        if (wv == 0) {
            unsigned long long b = (lane < 16) ? wmin[lane] : ~0ull;
#pragma unroll
            for (int off = 8; off > 0; off >>= 1) {
                unsigned long long o = __shfl_down(b, off, 64);
                b = (o < b) ? o : b;
            }
            if (lane == 0) { bcast = b; sh_idx[round] = (int)(b & 0xffffffffu); }
        }
        __syncthreads();
        const unsigned long long g = bcast;
#pragma unroll
        for (int j = 0; j < 25; ++j) if (key[j] == g) key[j] = ~0ull;
    }
    for (int e = tid; e < K * C; e += 1024) {
        int k = e >> 11, c = e & (C - 1);
        int id = sh_idx[k];
        float mb = (mask[id] > 0.0f) ? 1.0f : 0.0f;
        float v = X[(size_t)c * HW + id] * mb;
        g_cent[e] = v;
        g_cent64[e] = (double)v;
    }
    if (tid < K) g_counts[tid] = 0;
    if (tid == 0) g_done = 0u;
    __syncthreads();
    if (wv < K) {
        double a = 0.0;
        for (int c = lane; c < C; c += 64) {
            double v = (double)g_cent[wv * C + c];
            a = fma(v, v, a);
        }
#pragma unroll
        for (int off = 32; off > 0; off >>= 1) a += __shfl_down(a, off, 64);
        if (lane == 0) g_csq[wv] = (float)a;
    }
}

// ---------------- label pass 1: f64 partial dots, scalar-cached cent ----------------
// 800 blocks = 100 hw-blocks x 8 c-chunks of 256 channels; 1 token/thread.
// cent via wave-uniform f64 global loads (K$/s_load). cc-ascending f64 FMA.
__global__ __launch_bounds__(256) void label1_kernel(const float* __restrict__ X) {
    if (g_done) return;
    const int chunk = blockIdx.x & (NCH - 1);
    const int hw = (blockIdx.x >> 3) * 256 + threadIdx.x;
    const int c0 = chunk * CCH;
    const double* __restrict__ cp = g_cent64 + c0;  // [k*C + cc], wave-uniform
    double acc[K];
#pragma unroll
    for (int k = 0; k < K; ++k) acc[k] = 0.0;
    const float* xp = X + hw + (size_t)c0 * HW;
#pragma unroll 4
    for (int cc = 0; cc < CCH; ++cc) {
        const double x = (double)xp[(size_t)cc * HW];
#pragma unroll
        for (int k = 0; k < K; ++k) acc[k] = fma(x, cp[k * C + cc], acc[k]);
    }
#pragma unroll
    for (int k = 0; k < K; ++k) g_part[(chunk * K + k) * HW + hw] = acc[k];
}

// ---------------- label pass 2: combine 8, f32 d2 grid, argmin, hist ----------------
__global__ __launch_bounds__(256) void label2_kernel() {
#pragma clang fp contract(off)
    if (g_done) return;
    __shared__ int shist[K];
    const int t = threadIdx.x;
    if (t < K) shist[t] = 0;
    __syncthreads();
    const int hw = blockIdx.x * 256 + t;
    const float tsq = g_tok_sq[hw];
    float best = INFINITY;
    int bl = 0;
#pragma unroll
    for (int k = 0; k < K; ++k) {
        double p[NCH];
#pragma unroll
        for (int j = 0; j < NCH; ++j) p[j] = g_part[(j * K + k) * HW + hw];
        double d = ((p[0] + p[1]) + (p[2] + p[3])) + ((p[4] + p[5]) + (p[6] + p[7]));
        float dotf = (float)d;               // correctly-rounded f32 dot
        float twod = 2.0f * dotf;            // exact
        float d2 = (tsq - twod) + g_csq[k];  // reference's f32 grid
        if (d2 < best) { best = d2; bl = k; }
    }
    const int valid = g_valid[hw];
    g_labels[hw] = valid ? (unsigned char)bl : (unsigned char)255;
    if (valid) atomicAdd(&shist[bl], 1);
    __syncthreads();
    if (t < K) atomicAdd(&g_counts[t], shist[t]);
}

// ---------------- sum pass: block per channel, 4 waves x quarter-row ----------------
// 2048 blocks; 1600 float4/wave = 25/lane exact (no bounds check); LDS per-lane
// slots (stride 11, 2-way bank aliasing = free); f64 shuffle + quarter combine.
__global__ __launch_bounds__(256) void sum_kernel(const float* __restrict__ X) {
    if (g_done) return;
    __shared__ double sacc[4][64 * 11];  // 22.5 KB
    const int c = blockIdx.x;
    const int wv = threadIdx.x >> 6, lane = threadIdx.x & 63;
    double* slots = &sacc[wv][lane * 11];
#pragma unroll
    for (int k = 0; k < 11; ++k) slots[k] = 0.0;
    const int base = wv * (HW / 4);  // quarter-row (6400 elems = 1600 float4)
    const float4* xr = (const float4*)(X + (size_t)c * HW + base);
    const unsigned* lw = (const unsigned*)(g_labels + base);
    for (int t = 0; t < 25; ++t) {
        const int idx = t * 64 + lane;
        const float4 x = xr[idx];
        const unsigned w = lw[idx];
        const int l0 = min((int)(w & 255u), 10);
        const int l1 = min((int)((w >> 8) & 255u), 10);
        const int l2 = min((int)((w >> 16) & 255u), 10);
        const int l3 = min((int)(w >> 24), 10);
        slots[l0] += (double)x.x;
        slots[l1] += (double)x.y;
        slots[l2] += (double)x.z;
        slots[l3] += (double)x.w;
    }
    double acc[K];
#pragma unroll
    for (int k = 0; k < K; ++k) acc[k] = slots[k];
#pragma unroll
    for (int k = 0; k < K; ++k) {
#pragma unroll
        for (int off = 32; off > 0; off >>= 1) acc[k] += __shfl_down(acc[k], off, 64);
    }
    __shared__ double comb[4][K];
    if (lane == 0) {
#pragma unroll
        for (int k = 0; k < K; ++k) comb[wv][k] = acc[k];
    }
    __syncthreads();
    if (threadIdx.x < K) {
        const int k = threadIdx.x;
        g_spart[k * C + c] = (comb[0][k] + comb[1][k]) + (comb[2][k] + comb[3][k]);
    }
}

// ---------------- update / convergence / csq ----------------
__global__ __launch_bounds__(1024) void update_kernel(int last, float* __restrict__ out) {
#pragma clang fp contract(off)
    __shared__ float sh_counts[K];
    __shared__ int s_conv;
    __shared__ unsigned s_done;
    const int tid = threadIdx.x;
    if (tid == 0) { s_conv = 1; s_done = g_done; }
    if (tid < K) sh_counts[tid] = (float)g_counts[tid];
    __syncthreads();
    const bool dn = (s_done != 0);
    float newv[20], oldv[20];
    int convLocal = 1;
#pragma unroll
    for (int j = 0; j < 20; ++j) {
        int e = tid + j * 1024;
        int k = e >> 11;
        float cnt = sh_counts[k];
        float cv = g_cent[e];
        float sumf = (float)g_spart[e];   // f64 total -> f32 once
        float nv = (cnt > 0.0f) ? (sumf / fmaxf(cnt, 1.0f)) : cv;
        newv[j] = nv;
        oldv[j] = cv;
        float tol = RTOL_ * fabsf(nv);   // rounded mul
        tol = ATOL_ + tol;               // rounded add
        float diff = fabsf(cv - nv);
        if (!(diff <= tol)) convLocal = 0;
    }
    if (!convLocal) atomicAnd(&s_conv, 0);
    __syncthreads();
    const bool conv = (s_conv != 0);
    const bool upd = (!dn && !conv);
#pragma unroll
    for (int j = 0; j < 20; ++j) {
        int e = tid + j * 1024;
        float fv = upd ? newv[j] : oldv[j];
        if (upd) { g_cent[e] = fv; g_cent64[e] = (double)fv; }
        if (last) out[e] = fv;
    }
    if (tid == 0 && conv && !dn) g_done = 1u;
    if (tid < K) g_counts[tid] = 0;
    __syncthreads();
    const int wv = tid >> 6, lane = tid & 63;
    if (wv < K) {
        double a = 0.0;
        for (int c = lane; c < C; c += 64) {
            double v = (double)g_cent[wv * C + c];
            a = fma(v, v, a);
        }
#pragma unroll
        for (int off = 32; off > 0; off >>= 1) a += __shfl_down(a, off, 64);
        if (lane == 0) g_csq[wv] = (float)a;
    }
}

extern "C" void kernel_launch(void* const* d_in, const int* in_sizes, int n_in,
                              void* d_out, int out_size, void* d_ws, size_t ws_size,
                              hipStream_t stream) {
    const float* X = (const float*)d_in[0];     // [2048, 160*160] flat
    const float* mask = (const float*)d_in[1];  // [160*160]
    float* out = (float*)d_out;                 // [10, 2048]
    (void)in_sizes; (void)n_in; (void)out_size; (void)d_ws; (void)ws_size;

    prepA_kernel<<<800, 256, 0, stream>>>(X, mask);
    rng_kernel<<<100, 256, 0, stream>>>();
    select_kernel<<<1, 1024, 0, stream>>>(X, mask);
    for (int it = 0; it < NITER; ++it) {
        label1_kernel<<<800, 256, 0, stream>>>(X);
        label2_kernel<<<100, 256, 0, stream>>>();
        sum_kernel<<<C, 256, 0, stream>>>(X);
        update_kernel<<<1, 1024, 0, stream>>>(it == NITER - 1 ? 1 : 0, out);
    }
}